// Round 2
// baseline (149.406 us; speedup 1.0000x reference)
//
#include <hip/hip_runtime.h>
#include <hip/hip_bf16.h>
#include <stdint.h>

#define NTOT  8192
#define DIM   512
#define NI    8
#define NWAYS 1024
#define TILE  128
#define BK    64
#define NSYM  2080   /* 64*65/2 upper-triangle tile pairs */
#define NBLK  2592   /* NSYM + 512 proto blocks = 8 * 324 */
#define MARGINV 0.3f

typedef float f32x4 __attribute__((ext_vector_type(4)));

// order-preserving float<->uint map (monotonic for all finite floats +/- inf)
__device__ __forceinline__ unsigned f2o(float f) {
  unsigned u = __float_as_uint(f);
  return (u & 0x80000000u) ? ~u : (u | 0x80000000u);
}
__device__ __forceinline__ float o2f(unsigned u) {
  u = (u & 0x80000000u) ? (u & 0x7fffffffu) : ~u;
  return __uint_as_float(u);
}

__device__ __forceinline__ float wave_sum64(float v) {
#pragma unroll
  for (int s = 32; s; s >>= 1) v += __shfl_xor(v, s, 64);
  return v;
}

__device__ __forceinline__ void async_ld16(const void* g, void* l) {
  __builtin_amdgcn_global_load_lds(
      (__attribute__((address_space(1))) void*)(uintptr_t)g,
      (__attribute__((address_space(3))) void*)l, 16, 0, 0);
}

// ---- prep: sq-norms + fp8(e4m3) cast + accumulator init; protos in tail ----
__global__ __launch_bounds__(256) void prep(
    const float* __restrict__ A, float* __restrict__ sq,
    float* __restrict__ psq, unsigned char* __restrict__ A8,
    unsigned char* __restrict__ P8,
    unsigned* __restrict__ an_u32, unsigned* __restrict__ ap_u32,
    unsigned long long* __restrict__ pr_key) {
  const int w = threadIdx.x >> 6;
  const int l = threadIdx.x & 63;
  const int b = blockIdx.x;
  if (b < NTOT / 4) {
    const int row = b * 4 + w;
    const float4* rp = (const float4*)(A + (size_t)row * DIM);
    unsigned* op = (unsigned*)(A8 + (size_t)row * DIM);
    float s = 0.f;
#pragma unroll
    for (int m = 0; m < 2; ++m) {
      const float4 v = rp[l + 64 * m];
      s = fmaf(v.x, v.x, fmaf(v.y, v.y, fmaf(v.z, v.z, fmaf(v.w, v.w, s))));
      int wd = 0;
      wd = __builtin_amdgcn_cvt_pk_fp8_f32(v.x, v.y, wd, false);
      wd = __builtin_amdgcn_cvt_pk_fp8_f32(v.z, v.w, wd, true);
      op[l + 64 * m] = (unsigned)wd;
    }
    s = wave_sum64(s);
    if (l == 0) {
      sq[row] = s;
      an_u32[row] = ~0u;
      ap_u32[row] = 0u;
      pr_key[row] = ~0ull;
    }
  } else {
    const int c = (b - NTOT / 4) * 4 + w;  // proto id
    unsigned* op = (unsigned*)(P8 + (size_t)c * DIM);
    float s = 0.f;
#pragma unroll
    for (int m = 0; m < 2; ++m) {
      float4 p = {0.f, 0.f, 0.f, 0.f};
#pragma unroll
      for (int r = 0; r < NI; ++r) {
        const float4 v =
            ((const float4*)(A + (size_t)(c * NI + r) * DIM))[l + 64 * m];
        p.x += v.x; p.y += v.y; p.z += v.z; p.w += v.w;
      }
      p.x *= (1.f / NI); p.y *= (1.f / NI); p.z *= (1.f / NI); p.w *= (1.f / NI);
      s = fmaf(p.x, p.x, fmaf(p.y, p.y, fmaf(p.z, p.z, fmaf(p.w, p.w, s))));
      int wd = 0;
      wd = __builtin_amdgcn_cvt_pk_fp8_f32(p.x, p.y, wd, false);
      wd = __builtin_amdgcn_cvt_pk_fp8_f32(p.z, p.w, wd, true);
      op[l + 64 * m] = (unsigned)wd;
    }
    s = wave_sum64(s);
    if (l == 0) psq[c] = s;
  }
}

// ---- fused symmetric fp8 GEMM + min/max epilogues, BK=64 dbuf ----
// LDS layout: 64-B rows, 4x16-B units, unit u of row r stored at
// u ^ ((r ^ (r>>2)) & 3). Staging (global_load_lds) stays lane-linear in LDS
// (source pre-swizzled); fragment ds_read_b64 lands 2 lanes/bank per 32-lane
// phase (free). Key includes r>>2 so lanes lc and lc+4 (row stride 256 B = 0
// bank offset) land in different units.
// BK=64 cuts LDS to ~36 KB -> 4 blocks/CU (vs 2 at BK=128): the kernel is
// latency-bound with every pipe idle, so resident-wave count is the lever.
__global__ __launch_bounds__(256) void gemm_fused(
    const unsigned char* __restrict__ A, const unsigned char* __restrict__ P,
    const float* __restrict__ sq, const float* __restrict__ psq,
    unsigned* __restrict__ an_u32, unsigned* __restrict__ ap_u32,
    unsigned long long* __restrict__ pr_key) {
  __shared__ __align__(16) unsigned char As[2][TILE * BK];  // 2 x 8 KB
  __shared__ __align__(16) unsigned char Bs[2][TILE * BK];  // 2 x 8 KB
  __shared__ unsigned rmin[TILE];
  __shared__ unsigned cmin[TILE];
  __shared__ unsigned amax[TILE];
  __shared__ unsigned long long rowkey[TILE][2];  // proto path only

  const int braw = blockIdx.x;
  const int b = (braw & 7) * (NBLK / 8) + (braw >> 3);  // XCD-contiguous
  const bool isProto = b >= NSYM;
  int bi, bj;
  const unsigned char* Bmat;
  const float* sqB;
  if (!isProto) {
    // supertile decode: pairs (Si<=Sj) of 8x8-tile supertiles
    int rem = b, Si = 0, Sj = 0;
    for (;;) {
      const int cnt = (Si == Sj) ? 36 : 64;
      if (rem < cnt) break;
      rem -= cnt;
      ++Si;
      if (Si > Sj) { Si = 0; ++Sj; }
    }
    int bi_l, bj_l;
    if (Si == Sj) {
      bj_l = 0;
      while ((bj_l + 1) * (bj_l + 2) / 2 <= rem) ++bj_l;
      bi_l = rem - bj_l * (bj_l + 1) / 2;
    } else {
      bi_l = rem & 7;
      bj_l = rem >> 3;
    }
    bi = Si * 8 + bi_l;
    bj = Sj * 8 + bj_l;
    Bmat = A;
    sqB = sq;
  } else {
    const int p = b - NSYM;
    bj = p & 7;
    bi = p >> 3;
    Bmat = P;
    sqB = psq;
  }
  const int rowBase = bi * TILE;
  const int colBase = bj * TILE;
  const bool isDiag = !isProto && (bi == bj);
  const bool colSide = !isProto && (bi != bj);

  const int t = threadIdx.x;
  const int lane = t & 63;
  const int wv = t >> 6;
  const int wr = wv >> 1;
  const int wc = wv & 1;
  const int quad = lane >> 4;
  const int lc = lane & 15;

  if (t < TILE) { rmin[t] = ~0u; cmin[t] = ~0u; amax[t] = 0u; }

  // fragment-read unit offsets per 32-k chunk c:
  // logical unit = c*2 + (quad>>1); phys = logical ^ ((lc ^ (lc>>2)) & 3)
  const int kf = (lc ^ (lc >> 2)) & 3;
  int koff[2];
#pragma unroll
  for (int c = 0; c < 2; ++c)
    koff[c] = (((c * 2 + (quad >> 1)) ^ kf) * 16) + (quad & 1) * 8;

  int rowA[4], rowB[4];
#pragma unroll
  for (int x = 0; x < 4; ++x) {
    rowA[x] = (wr * 64 + x * 16 + lc) * BK;
    rowB[x] = (wc * 64 + x * 16 + lc) * BK;
  }

  // staging: lane covers (row = rr*16 + lane/4, phys unit = lane&3);
  // logical source unit = (lane&3) ^ key(row), key = (l4 ^ (l4>>2)) & 3.
  // Wave wv does rounds wv*2 .. wv*2+1 (8 rounds x 16 rows = 128 rows).
  const int l4 = lane >> 2;
  const int ul = ((lane & 3) ^ ((l4 ^ (l4 >> 2)) & 3)) * 16;
  const unsigned char* gA = A + (size_t)(rowBase + l4) * DIM + ul;
  const unsigned char* gB = Bmat + (size_t)(colBase + l4) * DIM + ul;
  const int ldsL = lane * 16;

  f32x4 acc[4][4] = {};

  // prologue: stage K-tile 0 into buffer 0
#pragma unroll
  for (int j = 0; j < 2; ++j) {
    const int rr = wv * 2 + j;
    async_ld16(gA + (size_t)rr * 16 * DIM, &As[0][rr * 1024 + ldsL]);
    async_ld16(gB + (size_t)rr * 16 * DIM, &Bs[0][rr * 1024 + ldsL]);
  }
  __syncthreads();

#pragma unroll
  for (int it = 0; it < 8; ++it) {
    const int cur = it & 1;
    const int nxt = cur ^ 1;
    const int kt = it * BK;
    if (it < 7) {  // issue-ahead next K-tile
#pragma unroll
      for (int j = 0; j < 2; ++j) {
        const int rr = wv * 2 + j;
        async_ld16(gA + (size_t)rr * 16 * DIM + kt + BK, &As[nxt][rr * 1024 + ldsL]);
        async_ld16(gB + (size_t)rr * 16 * DIM + kt + BK, &Bs[nxt][rr * 1024 + ldsL]);
      }
    }
    const unsigned char* Ac = &As[cur][0];
    const unsigned char* Bc = &Bs[cur][0];
#pragma unroll
    for (int c = 0; c < 2; ++c) {
      long af[4], bfr[4];
#pragma unroll
      for (int x = 0; x < 4; ++x) {
        af[x]  = *(const long*)(Ac + rowA[x] + koff[c]);
        bfr[x] = *(const long*)(Bc + rowB[x] + koff[c]);
      }
#pragma unroll
      for (int x = 0; x < 4; ++x)
#pragma unroll
        for (int y = 0; y < 4; ++y)
          acc[x][y] = __builtin_amdgcn_mfma_f32_16x16x32_fp8_fp8(
              af[x], bfr[y], acc[x][y], 0, 0, 0);
    }
    __syncthreads();  // publishes buf[nxt]; all reads of buf[cur] done
  }

  // ---- epilogue. C/D layout: col=lane&15, row=quad*4+reg ----
  float sb[4];
#pragma unroll
  for (int y = 0; y < 4; ++y) sb[y] = sqB[colBase + wc * 64 + y * 16 + lc];

  const float INF = __int_as_float(0x7f800000);

  if (!isProto) {
    // row-side: butterfly min over the 16-lane quad (lanes differ in lc =
    // column), then ONE active lane per quad does the LDS atomic -> 4
    // distinct addresses per instruction, no same-address serialization.
#pragma unroll
    for (int x = 0; x < 4; ++x) {
#pragma unroll
      for (int r = 0; r < 4; ++r) {
        const int row = rowBase + wr * 64 + x * 16 + quad * 4 + r;
        float mv = INF, mx = -INF;
#pragma unroll
        for (int y = 0; y < 4; ++y) {
          const float v = fmaf(-2.f, acc[x][y][r], sb[y]);
          if (isDiag) {
            const int col = colBase + wc * 64 + y * 16 + lc;
            const bool same = (row >> 3) == (col >> 3);
            mv = fminf(mv, same ? INF : v);
            mx = fmaxf(mx, same ? v : -INF);
          } else {
            mv = fminf(mv, v);
          }
        }
#pragma unroll
        for (int s = 1; s < 16; s <<= 1) {
          mv = fminf(mv, __shfl_xor(mv, s, 64));
          if (isDiag) mx = fmaxf(mx, __shfl_xor(mx, s, 64));
        }
        if (lc == 0) {
          atomicMin(&rmin[row - rowBase], f2o(mv));
          if (isDiag) atomicMax(&amax[row - rowBase], f2o(mx));
        }
      }
    }
    // col-side (off-diag): per-lane min over (x,r) per y; same column is
    // held by the 4 quads -> reduce across quads, then quad 0 atomics to
    // 16 distinct addresses.
    if (colSide) {
      float sa[4][4];
#pragma unroll
      for (int x = 0; x < 4; ++x)
#pragma unroll
        for (int r = 0; r < 4; ++r)
          sa[x][r] = sq[rowBase + wr * 64 + x * 16 + quad * 4 + r];
#pragma unroll
      for (int y = 0; y < 4; ++y) {
        float cv = INF;
#pragma unroll
        for (int x = 0; x < 4; ++x)
#pragma unroll
          for (int r = 0; r < 4; ++r)
            cv = fminf(cv, fmaf(-2.f, acc[x][y][r], sa[x][r]));
        cv = fminf(cv, __shfl_xor(cv, 16, 64));
        cv = fminf(cv, __shfl_xor(cv, 32, 64));
        if (quad == 0) atomicMin(&cmin[wc * 64 + y * 16 + lc], f2o(cv));
      }
    }
  } else {
    // proto path: need argmin index -> u64 keys + 16-lane butterfly
#pragma unroll
    for (int x = 0; x < 4; ++x) {
      unsigned long long kmin[4] = {~0ull, ~0ull, ~0ull, ~0ull};
#pragma unroll
      for (int y = 0; y < 4; ++y) {
        const int col = colBase + wc * 64 + y * 16 + lc;
#pragma unroll
        for (int r = 0; r < 4; ++r) {
          const float v = fmaf(-2.f, acc[x][y][r], sb[y]);
          const unsigned long long kn =
              ((unsigned long long)f2o(v) << 32) | (unsigned)col;
          if (kn < kmin[r]) kmin[r] = kn;
        }
      }
#pragma unroll
      for (int r = 0; r < 4; ++r) {
#pragma unroll
        for (int s = 1; s < 16; s <<= 1) {
          const unsigned long long o = __shfl_xor(kmin[r], s, 64);
          if (o < kmin[r]) kmin[r] = o;
        }
      }
      if (lc == 0) {
#pragma unroll
        for (int r = 0; r < 4; ++r)
          rowkey[wr * 64 + x * 16 + quad * 4 + r][wc] = kmin[r];
      }
    }
  }

  __syncthreads();
  if (isProto) {
    if (t < TILE) {
      unsigned long long a = rowkey[t][0];
      const unsigned long long c = rowkey[t][1];
      if (c < a) a = c;
      atomicMin(pr_key + rowBase + t, a);
    }
  } else {
    if (t < TILE) {
      atomicMin(an_u32 + rowBase + t, rmin[t]);
    } else if (t < 2 * TILE) {
      const int i = t - TILE;
      if (colSide) atomicMin(an_u32 + colBase + i, cmin[i]);
      else if (isDiag) atomicMax(ap_u32 + rowBase + i, amax[i]);
    }
  }
}

// ---- final scalar reductions ----
__global__ void finalize_kernel(const float* __restrict__ sq,
                                const unsigned* __restrict__ an_u32,
                                const unsigned* __restrict__ ap_u32,
                                const unsigned long long* __restrict__ pr_key,
                                float* __restrict__ out) {
  const int tid = threadIdx.x;  // 1024 threads
  float loss = 0.f, sp = 0.f, sn = 0.f, acc = 0.f;
#pragma unroll
  for (int i = tid; i < NTOT; i += 1024) {
    const float s = sq[i];
    const float ap = sqrtf(fmaxf(s + o2f(ap_u32[i]), 1e-12f));
    const float an = sqrtf(fmaxf(s + o2f(an_u32[i]), 1e-12f));
    loss += fmaxf(ap - an + MARGINV, 0.f);
    sp += ap;
    sn += an;
    acc += ((unsigned)(pr_key[i] & 0xffffffffu) == (unsigned)(i >> 3)) ? 1.f : 0.f;
  }
  loss = wave_sum64(loss);
  sp = wave_sum64(sp);
  sn = wave_sum64(sn);
  acc = wave_sum64(acc);
  __shared__ float red[16][4];
  const int w = tid >> 6, l = tid & 63;
  if (l == 0) { red[w][0] = loss; red[w][1] = acc; red[w][2] = sp; red[w][3] = sn; }
  __syncthreads();
  if (tid == 0) {
    float L = 0, Ac = 0, Pm = 0, Nn = 0;
    for (int i = 0; i < 16; ++i) {
      L += red[i][0]; Ac += red[i][1]; Pm += red[i][2]; Nn += red[i][3];
    }
    out[0] = L / NTOT;   // W = 1.0
    out[1] = Ac / NTOT;
    out[2] = Pm / NTOT;
    out[3] = Nn / NTOT;
  }
}

extern "C" void kernel_launch(void* const* d_in, const int* in_sizes, int n_in,
                              void* d_out, int out_size, void* d_ws, size_t ws_size,
                              hipStream_t stream) {
  const float* inputs = (const float*)d_in[0];
  float* out = (float*)d_out;
  char* w = (char*)d_ws;
  float* sq  = (float*)(w);                                       // 32 KB
  float* psq = (float*)(w + 32768);                               // 4 KB
  unsigned* an_u32 = (unsigned*)(w + 36864);                      // 32 KB
  unsigned* ap_u32 = (unsigned*)(w + 69632);                      // 32 KB
  unsigned long long* pr_key = (unsigned long long*)(w + 102400); // 64 KB
  unsigned char* A8 = (unsigned char*)(w + 167936);               // 4 MB
  unsigned char* P8 = (unsigned char*)(w + 167936 + (size_t)NTOT * DIM);

  prep<<<NTOT / 4 + NWAYS / 4, 256, 0, stream>>>(inputs, sq, psq, A8, P8,
                                                 an_u32, ap_u32, pr_key);
  gemm_fused<<<NBLK, 256, 0, stream>>>(A8, P8, sq, psq,
                                       an_u32, ap_u32, pr_key);
  finalize_kernel<<<1, 1024, 0, stream>>>(sq, an_u32, ap_u32, pr_key, out);
}

// Round 3
// 146.964 us; speedup vs baseline: 1.0166x; 1.0166x over previous
//
#include <hip/hip_runtime.h>
#include <hip/hip_bf16.h>
#include <stdint.h>

#define NTOT  8192
#define DIM   512
#define NI    8
#define NWAYS 1024
#define TILE  128
#define BK    64
#define NBUF  3
#define NSYM  2080   /* 64*65/2 upper-triangle tile pairs */
#define NBLK  2592   /* NSYM + 512 proto blocks = 8 * 324 */
#define MARGINV 0.3f

typedef float f32x4 __attribute__((ext_vector_type(4)));

// counted-vmcnt barrier: wait for all but N outstanding VMEM ops, then raw
// s_barrier. Single asm so the compiler cannot interleave anything between
// the wait and the barrier, and "memory" pins LDS reads/writes on each side.
#define VMWAIT_BAR(N) \
  asm volatile("s_waitcnt vmcnt(" #N ")\n\ts_barrier" ::: "memory")

// order-preserving float<->uint map (monotonic for all finite floats +/- inf)
__device__ __forceinline__ unsigned f2o(float f) {
  unsigned u = __float_as_uint(f);
  return (u & 0x80000000u) ? ~u : (u | 0x80000000u);
}
__device__ __forceinline__ float o2f(unsigned u) {
  u = (u & 0x80000000u) ? (u & 0x7fffffffu) : ~u;
  return __uint_as_float(u);
}

__device__ __forceinline__ float wave_sum64(float v) {
#pragma unroll
  for (int s = 32; s; s >>= 1) v += __shfl_xor(v, s, 64);
  return v;
}

__device__ __forceinline__ void async_ld16(const void* g, void* l) {
  __builtin_amdgcn_global_load_lds(
      (__attribute__((address_space(1))) void*)(uintptr_t)g,
      (__attribute__((address_space(3))) void*)l, 16, 0, 0);
}

// ---- prep: sq-norms + fp8(e4m3) cast + accumulator init; protos in tail ----
__global__ __launch_bounds__(256) void prep(
    const float* __restrict__ A, float* __restrict__ sq,
    float* __restrict__ psq, unsigned char* __restrict__ A8,
    unsigned char* __restrict__ P8,
    unsigned* __restrict__ an_u32, unsigned* __restrict__ ap_u32,
    unsigned long long* __restrict__ pr_key) {
  const int w = threadIdx.x >> 6;
  const int l = threadIdx.x & 63;
  const int b = blockIdx.x;
  if (b < NTOT / 4) {
    const int row = b * 4 + w;
    const float4* rp = (const float4*)(A + (size_t)row * DIM);
    unsigned* op = (unsigned*)(A8 + (size_t)row * DIM);
    float s = 0.f;
#pragma unroll
    for (int m = 0; m < 2; ++m) {
      const float4 v = rp[l + 64 * m];
      s = fmaf(v.x, v.x, fmaf(v.y, v.y, fmaf(v.z, v.z, fmaf(v.w, v.w, s))));
      int wd = 0;
      wd = __builtin_amdgcn_cvt_pk_fp8_f32(v.x, v.y, wd, false);
      wd = __builtin_amdgcn_cvt_pk_fp8_f32(v.z, v.w, wd, true);
      op[l + 64 * m] = (unsigned)wd;
    }
    s = wave_sum64(s);
    if (l == 0) {
      sq[row] = s;
      an_u32[row] = ~0u;
      ap_u32[row] = 0u;
      pr_key[row] = ~0ull;
    }
  } else {
    const int c = (b - NTOT / 4) * 4 + w;  // proto id
    unsigned* op = (unsigned*)(P8 + (size_t)c * DIM);
    float s = 0.f;
#pragma unroll
    for (int m = 0; m < 2; ++m) {
      float4 p = {0.f, 0.f, 0.f, 0.f};
#pragma unroll
      for (int r = 0; r < NI; ++r) {
        const float4 v =
            ((const float4*)(A + (size_t)(c * NI + r) * DIM))[l + 64 * m];
        p.x += v.x; p.y += v.y; p.z += v.z; p.w += v.w;
      }
      p.x *= (1.f / NI); p.y *= (1.f / NI); p.z *= (1.f / NI); p.w *= (1.f / NI);
      s = fmaf(p.x, p.x, fmaf(p.y, p.y, fmaf(p.z, p.z, fmaf(p.w, p.w, s))));
      int wd = 0;
      wd = __builtin_amdgcn_cvt_pk_fp8_f32(p.x, p.y, wd, false);
      wd = __builtin_amdgcn_cvt_pk_fp8_f32(p.z, p.w, wd, true);
      op[l + 64 * m] = (unsigned)wd;
    }
    s = wave_sum64(s);
    if (l == 0) psq[c] = s;
  }
}

// ---- fused symmetric fp8 GEMM + min/max epilogues ----
// K-loop: BK=64, 3-buffer ring, ONE raw s_barrier per K-step with COUNTED
// s_waitcnt vmcnt(4) (T3+T4): loads for tile t+1 stay in flight across the
// barrier; only tile t's 4 loads are drained. Buffer-reuse proof: tile t+2
// is issued into buf[(t+2)%3] == buf[(t-1)%3] AFTER the iter-t barrier;
// every wave consumed its tile-(t-1) fragments in its iter-(t-1) MFMAs
// (compiler lgkmcnt before use) before arriving at that barrier.
// LDS layout per tile: 64-B rows, 4x16-B units, unit u of row r stored at
// u ^ ((r ^ (r>>2)) & 3); staging lane-linear in LDS, source pre-swizzled.
__global__ __launch_bounds__(256) void gemm_fused(
    const unsigned char* __restrict__ A, const unsigned char* __restrict__ P,
    const float* __restrict__ sq, const float* __restrict__ psq,
    unsigned* __restrict__ an_u32, unsigned* __restrict__ ap_u32,
    unsigned long long* __restrict__ pr_key) {
  __shared__ __align__(16) unsigned char As[NBUF][TILE * BK];  // 3 x 8 KB
  __shared__ __align__(16) unsigned char Bs[NBUF][TILE * BK];  // 3 x 8 KB
  __shared__ unsigned rmin[TILE];
  __shared__ unsigned cmin[TILE];
  __shared__ unsigned amax[TILE];
  __shared__ unsigned long long rowkey[TILE][2];  // proto path only

  const int braw = blockIdx.x;
  const int b = (braw & 7) * (NBLK / 8) + (braw >> 3);  // XCD-contiguous
  const bool isProto = b >= NSYM;
  int bi, bj;
  const unsigned char* Bmat;
  const float* sqB;
  if (!isProto) {
    // supertile decode: pairs (Si<=Sj) of 8x8-tile supertiles
    int rem = b, Si = 0, Sj = 0;
    for (;;) {
      const int cnt = (Si == Sj) ? 36 : 64;
      if (rem < cnt) break;
      rem -= cnt;
      ++Si;
      if (Si > Sj) { Si = 0; ++Sj; }
    }
    int bi_l, bj_l;
    if (Si == Sj) {
      bj_l = 0;
      while ((bj_l + 1) * (bj_l + 2) / 2 <= rem) ++bj_l;
      bi_l = rem - bj_l * (bj_l + 1) / 2;
    } else {
      bi_l = rem & 7;
      bj_l = rem >> 3;
    }
    bi = Si * 8 + bi_l;
    bj = Sj * 8 + bj_l;
    Bmat = A;
    sqB = sq;
  } else {
    const int p = b - NSYM;
    bj = p & 7;
    bi = p >> 3;
    Bmat = P;
    sqB = psq;
  }
  const int rowBase = bi * TILE;
  const int colBase = bj * TILE;
  const bool isDiag = !isProto && (bi == bj);
  const bool colSide = !isProto && (bi != bj);

  const int t = threadIdx.x;
  const int lane = t & 63;
  const int wv = t >> 6;
  const int wr = wv >> 1;
  const int wc = wv & 1;
  const int quad = lane >> 4;
  const int lc = lane & 15;

  if (t < TILE) { rmin[t] = ~0u; cmin[t] = ~0u; amax[t] = 0u; }

  // ---- epilogue operands issued FIRST (oldest in vmcnt order, so the
  // iter-0 vmcnt wait drains them; their latency hides under the K-loop) ----
  float sb[4];
#pragma unroll
  for (int y = 0; y < 4; ++y) sb[y] = sqB[colBase + wc * 64 + y * 16 + lc];
  float sa[4][4];
  if (colSide) {
#pragma unroll
    for (int x = 0; x < 4; ++x)
#pragma unroll
      for (int r = 0; r < 4; ++r)
        sa[x][r] = sq[rowBase + wr * 64 + x * 16 + quad * 4 + r];
  }
  asm volatile("" ::: "memory");  // keep the loads above the staging issues

  // fragment-read unit offsets per 32-k chunk c:
  // logical unit = c*2 + (quad>>1); phys = logical ^ ((lc ^ (lc>>2)) & 3)
  const int kf = (lc ^ (lc >> 2)) & 3;
  int koff[2];
#pragma unroll
  for (int c = 0; c < 2; ++c)
    koff[c] = (((c * 2 + (quad >> 1)) ^ kf) * 16) + (quad & 1) * 8;

  int rowA[4], rowB[4];
#pragma unroll
  for (int x = 0; x < 4; ++x) {
    rowA[x] = (wr * 64 + x * 16 + lc) * BK;
    rowB[x] = (wc * 64 + x * 16 + lc) * BK;
  }

  // staging: lane covers (row = rr*16 + lane/4, phys unit = lane&3);
  // logical source unit = (lane&3) ^ key(row), key = (l4 ^ (l4>>2)) & 3.
  // Wave wv does rounds wv*2 .. wv*2+1 (8 rounds x 16 rows = 128 rows).
  const int l4 = lane >> 2;
  const int ul = ((lane & 3) ^ ((l4 ^ (l4 >> 2)) & 3)) * 16;
  const unsigned char* gA = A + (size_t)(rowBase + l4) * DIM + ul;
  const unsigned char* gB = Bmat + (size_t)(colBase + l4) * DIM + ul;
  const int ldsL = lane * 16;

  f32x4 acc[4][4] = {};

  // prologue: stage K-tiles 0 and 1 into buffers 0 and 1 (4 loads each/wave)
#pragma unroll
  for (int tt = 0; tt < 2; ++tt) {
#pragma unroll
    for (int j = 0; j < 2; ++j) {
      const int rr = wv * 2 + j;
      async_ld16(gA + (size_t)rr * 16 * DIM + tt * BK, &As[tt][rr * 1024 + ldsL]);
      async_ld16(gB + (size_t)rr * 16 * DIM + tt * BK, &Bs[tt][rr * 1024 + ldsL]);
    }
  }

#pragma unroll
  for (int it = 0; it < 8; ++it) {
    // tile `it` fully staged after this; tile it+1's 4 loads stay in flight
    if (it < 7) VMWAIT_BAR(4);
    else       VMWAIT_BAR(0);
    if (it < 6) {  // issue tile it+2 into buf[(it+2)%3] (proven free above)
      const int nb = (it + 2) % NBUF;
      const int kt2 = (it + 2) * BK;
#pragma unroll
      for (int j = 0; j < 2; ++j) {
        const int rr = wv * 2 + j;
        async_ld16(gA + (size_t)rr * 16 * DIM + kt2, &As[nb][rr * 1024 + ldsL]);
        async_ld16(gB + (size_t)rr * 16 * DIM + kt2, &Bs[nb][rr * 1024 + ldsL]);
      }
    }
    const unsigned char* Ac = &As[it % NBUF][0];
    const unsigned char* Bc = &Bs[it % NBUF][0];
#pragma unroll
    for (int c = 0; c < 2; ++c) {
      long af[4], bfr[4];
#pragma unroll
      for (int x = 0; x < 4; ++x) {
        af[x]  = *(const long*)(Ac + rowA[x] + koff[c]);
        bfr[x] = *(const long*)(Bc + rowB[x] + koff[c]);
      }
      __builtin_amdgcn_s_setprio(1);
#pragma unroll
      for (int x = 0; x < 4; ++x)
#pragma unroll
        for (int y = 0; y < 4; ++y)
          acc[x][y] = __builtin_amdgcn_mfma_f32_16x16x32_fp8_fp8(
              af[x], bfr[y], acc[x][y], 0, 0, 0);
      __builtin_amdgcn_s_setprio(0);
    }
  }

  // ---- epilogue. C/D layout: col=lane&15, row=quad*4+reg ----
  const float INF = __int_as_float(0x7f800000);

  if (!isProto) {
    // row-side: butterfly min over the 16-lane quad (lanes differ in lc =
    // column), then ONE active lane per quad does the LDS atomic -> 4
    // distinct addresses per instruction, no same-address serialization.
#pragma unroll
    for (int x = 0; x < 4; ++x) {
#pragma unroll
      for (int r = 0; r < 4; ++r) {
        const int row = rowBase + wr * 64 + x * 16 + quad * 4 + r;
        float mv = INF, mx = -INF;
#pragma unroll
        for (int y = 0; y < 4; ++y) {
          const float v = fmaf(-2.f, acc[x][y][r], sb[y]);
          if (isDiag) {
            const int col = colBase + wc * 64 + y * 16 + lc;
            const bool same = (row >> 3) == (col >> 3);
            mv = fminf(mv, same ? INF : v);
            mx = fmaxf(mx, same ? v : -INF);
          } else {
            mv = fminf(mv, v);
          }
        }
#pragma unroll
        for (int s = 1; s < 16; s <<= 1) {
          mv = fminf(mv, __shfl_xor(mv, s, 64));
          if (isDiag) mx = fmaxf(mx, __shfl_xor(mx, s, 64));
        }
        if (lc == 0) {
          atomicMin(&rmin[row - rowBase], f2o(mv));
          if (isDiag) atomicMax(&amax[row - rowBase], f2o(mx));
        }
      }
    }
    // col-side (off-diag): per-lane min over (x,r) per y; same column is
    // held by the 4 quads -> reduce across quads, then quad 0 atomics to
    // 16 distinct addresses.
    if (colSide) {
#pragma unroll
      for (int y = 0; y < 4; ++y) {
        float cv = INF;
#pragma unroll
        for (int x = 0; x < 4; ++x)
#pragma unroll
          for (int r = 0; r < 4; ++r)
            cv = fminf(cv, fmaf(-2.f, acc[x][y][r], sa[x][r]));
        cv = fminf(cv, __shfl_xor(cv, 16, 64));
        cv = fminf(cv, __shfl_xor(cv, 32, 64));
        if (quad == 0) atomicMin(&cmin[wc * 64 + y * 16 + lc], f2o(cv));
      }
    }
  } else {
    // proto path: need argmin index -> u64 keys + 16-lane butterfly
#pragma unroll
    for (int x = 0; x < 4; ++x) {
      unsigned long long kmin[4] = {~0ull, ~0ull, ~0ull, ~0ull};
#pragma unroll
      for (int y = 0; y < 4; ++y) {
        const int col = colBase + wc * 64 + y * 16 + lc;
#pragma unroll
        for (int r = 0; r < 4; ++r) {
          const float v = fmaf(-2.f, acc[x][y][r], sb[y]);
          const unsigned long long kn =
              ((unsigned long long)f2o(v) << 32) | (unsigned)col;
          if (kn < kmin[r]) kmin[r] = kn;
        }
      }
#pragma unroll
      for (int r = 0; r < 4; ++r) {
#pragma unroll
        for (int s = 1; s < 16; s <<= 1) {
          const unsigned long long o = __shfl_xor(kmin[r], s, 64);
          if (o < kmin[r]) kmin[r] = o;
        }
      }
      if (lc == 0) {
#pragma unroll
        for (int r = 0; r < 4; ++r)
          rowkey[wr * 64 + x * 16 + quad * 4 + r][wc] = kmin[r];
      }
    }
  }

  __syncthreads();
  if (isProto) {
    if (t < TILE) {
      unsigned long long a = rowkey[t][0];
      const unsigned long long c = rowkey[t][1];
      if (c < a) a = c;
      atomicMin(pr_key + rowBase + t, a);
    }
  } else {
    if (t < TILE) {
      atomicMin(an_u32 + rowBase + t, rmin[t]);
    } else if (t < 2 * TILE) {
      const int i = t - TILE;
      if (colSide) atomicMin(an_u32 + colBase + i, cmin[i]);
      else if (isDiag) atomicMax(ap_u32 + rowBase + i, amax[i]);
    }
  }
}

// ---- final scalar reductions ----
__global__ void finalize_kernel(const float* __restrict__ sq,
                                const unsigned* __restrict__ an_u32,
                                const unsigned* __restrict__ ap_u32,
                                const unsigned long long* __restrict__ pr_key,
                                float* __restrict__ out) {
  const int tid = threadIdx.x;  // 1024 threads
  float loss = 0.f, sp = 0.f, sn = 0.f, acc = 0.f;
#pragma unroll
  for (int i = tid; i < NTOT; i += 1024) {
    const float s = sq[i];
    const float ap = sqrtf(fmaxf(s + o2f(ap_u32[i]), 1e-12f));
    const float an = sqrtf(fmaxf(s + o2f(an_u32[i]), 1e-12f));
    loss += fmaxf(ap - an + MARGINV, 0.f);
    sp += ap;
    sn += an;
    acc += ((unsigned)(pr_key[i] & 0xffffffffu) == (unsigned)(i >> 3)) ? 1.f : 0.f;
  }
  loss = wave_sum64(loss);
  sp = wave_sum64(sp);
  sn = wave_sum64(sn);
  acc = wave_sum64(acc);
  __shared__ float red[16][4];
  const int w = tid >> 6, l = tid & 63;
  if (l == 0) { red[w][0] = loss; red[w][1] = acc; red[w][2] = sp; red[w][3] = sn; }
  __syncthreads();
  if (tid == 0) {
    float L = 0, Ac = 0, Pm = 0, Nn = 0;
    for (int i = 0; i < 16; ++i) {
      L += red[i][0]; Ac += red[i][1]; Pm += red[i][2]; Nn += red[i][3];
    }
    out[0] = L / NTOT;   // W = 1.0
    out[1] = Ac / NTOT;
    out[2] = Pm / NTOT;
    out[3] = Nn / NTOT;
  }
}

extern "C" void kernel_launch(void* const* d_in, const int* in_sizes, int n_in,
                              void* d_out, int out_size, void* d_ws, size_t ws_size,
                              hipStream_t stream) {
  const float* inputs = (const float*)d_in[0];
  float* out = (float*)d_out;
  char* w = (char*)d_ws;
  float* sq  = (float*)(w);                                       // 32 KB
  float* psq = (float*)(w + 32768);                               // 4 KB
  unsigned* an_u32 = (unsigned*)(w + 36864);                      // 32 KB
  unsigned* ap_u32 = (unsigned*)(w + 69632);                      // 32 KB
  unsigned long long* pr_key = (unsigned long long*)(w + 102400); // 64 KB
  unsigned char* A8 = (unsigned char*)(w + 167936);               // 4 MB
  unsigned char* P8 = (unsigned char*)(w + 167936 + (size_t)NTOT * DIM);

  prep<<<NTOT / 4 + NWAYS / 4, 256, 0, stream>>>(inputs, sq, psq, A8, P8,
                                                 an_u32, ap_u32, pr_key);
  gemm_fused<<<NBLK, 256, 0, stream>>>(A8, P8, sq, psq,
                                       an_u32, ap_u32, pr_key);
  finalize_kernel<<<1, 1024, 0, stream>>>(sq, an_u32, ap_u32, pr_key, out);
}

// Round 4
// 144.398 us; speedup vs baseline: 1.0347x; 1.0178x over previous
//
#include <hip/hip_runtime.h>
#include <hip/hip_bf16.h>
#include <stdint.h>

#define NTOT  8192
#define DIM   512
#define NI    8
#define NWAYS 1024
#define BM    256
#define BN    128
#define BK    128
#define NBUF  3
#define NSYM2 1056   /* sum_{I=0}^{31} (64-2I): 256-row x 128-col upper blocks */
#define NBLK2 1312   /* NSYM2 + 256 proto blocks; 1312 = 8*164 */
#define MARGINV 0.3f

typedef float f32x4 __attribute__((ext_vector_type(4)));

// counted-vmcnt barrier: wait for all but N outstanding VMEM ops, then raw
// s_barrier, in one asm so nothing is scheduled between them.
#define VMWAIT_BAR(N) \
  asm volatile("s_waitcnt vmcnt(" #N ")\n\ts_barrier" ::: "memory")

// order-preserving float<->uint map (monotonic for all finite floats +/- inf)
__device__ __forceinline__ unsigned f2o(float f) {
  unsigned u = __float_as_uint(f);
  return (u & 0x80000000u) ? ~u : (u | 0x80000000u);
}
__device__ __forceinline__ float o2f(unsigned u) {
  u = (u & 0x80000000u) ? (u & 0x7fffffffu) : ~u;
  return __uint_as_float(u);
}

__device__ __forceinline__ float wave_sum64(float v) {
#pragma unroll
  for (int s = 32; s; s >>= 1) v += __shfl_xor(v, s, 64);
  return v;
}

__device__ __forceinline__ void async_ld16(const void* g, void* l) {
  __builtin_amdgcn_global_load_lds(
      (__attribute__((address_space(1))) void*)(uintptr_t)g,
      (__attribute__((address_space(3))) void*)l, 16, 0, 0);
}

// ---- prep: sq-norms + fp8(e4m3) cast + accumulator init; protos in tail ----
__global__ __launch_bounds__(256) void prep(
    const float* __restrict__ A, float* __restrict__ sq,
    float* __restrict__ psq, unsigned char* __restrict__ A8,
    unsigned char* __restrict__ P8,
    unsigned* __restrict__ an_u32, unsigned* __restrict__ ap_u32,
    unsigned long long* __restrict__ pr_key) {
  const int w = threadIdx.x >> 6;
  const int l = threadIdx.x & 63;
  const int b = blockIdx.x;
  if (b < NTOT / 4) {
    const int row = b * 4 + w;
    const float4* rp = (const float4*)(A + (size_t)row * DIM);
    unsigned* op = (unsigned*)(A8 + (size_t)row * DIM);
    float s = 0.f;
#pragma unroll
    for (int m = 0; m < 2; ++m) {
      const float4 v = rp[l + 64 * m];
      s = fmaf(v.x, v.x, fmaf(v.y, v.y, fmaf(v.z, v.z, fmaf(v.w, v.w, s))));
      int wd = 0;
      wd = __builtin_amdgcn_cvt_pk_fp8_f32(v.x, v.y, wd, false);
      wd = __builtin_amdgcn_cvt_pk_fp8_f32(v.z, v.w, wd, true);
      op[l + 64 * m] = (unsigned)wd;
    }
    s = wave_sum64(s);
    if (l == 0) {
      sq[row] = s;
      an_u32[row] = ~0u;
      ap_u32[row] = 0u;
      pr_key[row] = ~0ull;
    }
  } else {
    const int c = (b - NTOT / 4) * 4 + w;  // proto id
    unsigned* op = (unsigned*)(P8 + (size_t)c * DIM);
    float s = 0.f;
#pragma unroll
    for (int m = 0; m < 2; ++m) {
      float4 p = {0.f, 0.f, 0.f, 0.f};
#pragma unroll
      for (int r = 0; r < NI; ++r) {
        const float4 v =
            ((const float4*)(A + (size_t)(c * NI + r) * DIM))[l + 64 * m];
        p.x += v.x; p.y += v.y; p.z += v.z; p.w += v.w;
      }
      p.x *= (1.f / NI); p.y *= (1.f / NI); p.z *= (1.f / NI); p.w *= (1.f / NI);
      s = fmaf(p.x, p.x, fmaf(p.y, p.y, fmaf(p.z, p.z, fmaf(p.w, p.w, s))));
      int wd = 0;
      wd = __builtin_amdgcn_cvt_pk_fp8_f32(p.x, p.y, wd, false);
      wd = __builtin_amdgcn_cvt_pk_fp8_f32(p.z, p.w, wd, true);
      op[l + 64 * m] = (unsigned)wd;
    }
    s = wave_sum64(s);
    if (l == 0) psq[c] = s;
  }
}

// ---- fused symmetric fp8 GEMM, 256x128 tiles, 8 waves, BK=128 ring ----
// Rationale: the kernel is staging-supply-bound (~4.5 TB/s achieved LDS
// staging vs 15.6 TB/s needed at 128 FLOP/byte). 256x128 tiles raise
// arithmetic intensity to 171 FLOP/byte and halve per-block fixed costs.
// Symmetric cover: block (I, J>=2I) computes panel pairs (2I,J),(2I+1,J);
// the one duplicated 128-tile per I is harmless (min/max idempotent).
// LDS layout per tile row: 128-B rows, 8x16-B units, unit u of row r at
// u^(r&7); staging lane-linear in LDS with pre-swizzled global source;
// fragment ds_read_b64 recovers identical logical k for A and B.
__global__ __launch_bounds__(512) void gemm_fused(
    const unsigned char* __restrict__ A, const unsigned char* __restrict__ P,
    const float* __restrict__ sq, const float* __restrict__ psq,
    unsigned* __restrict__ an_u32, unsigned* __restrict__ ap_u32,
    unsigned long long* __restrict__ pr_key) {
  __shared__ __align__(16) unsigned char As[NBUF][BM * BK];  // 3 x 32 KB
  __shared__ __align__(16) unsigned char Bs[NBUF][BN * BK];  // 3 x 16 KB
  __shared__ unsigned rmin[BM];
  __shared__ unsigned cmin[BN];
  __shared__ unsigned amax[BM];
  __shared__ unsigned long long rowkey[BM][2];  // proto path only

  const int braw = blockIdx.x;
  const int b = (braw & 7) * (NBLK2 / 8) + (braw >> 3);  // XCD-contiguous
  const bool isProto = b >= NSYM2;
  int I, J;
  const unsigned char* Bmat;
  const float* sqB;
  if (!isProto) {
    int rem = b, i = 0;
    while (rem >= 64 - 2 * i) { rem -= 64 - 2 * i; ++i; }  // <=32 iters
    I = i;
    J = 2 * i + rem;
    Bmat = A;
    sqB = sq;
  } else {
    const int p = b - NSYM2;
    I = p >> 3;
    J = p & 7;
    Bmat = P;
    sqB = psq;
  }
  const int rowBase = I * BM;
  const int colBase = J * BN;
  const int dh = J - 2 * I;  // 0/1 => which 128-row half is diagonal
  const bool hasDiag = !isProto && (unsigned)dh <= 1u;

  const int t = threadIdx.x;  // 512 threads = 8 waves
  const int lane = t & 63;
  const int wv = t >> 6;      // 0..7
  const int wr = wv >> 1;     // 0..3: 64-row slice of 256
  const int wc = wv & 1;      // 0..1: 64-col slice of 128
  const int quad = lane >> 4;
  const int lc = lane & 15;
  // this wave's 128-row panel: 2I + (wr>>1); diagonal iff == J
  const bool diagHalf = !isProto && (2 * I + (wr >> 1)) == J;

  if (t < BM) { rmin[t] = ~0u; amax[t] = 0u; }
  if (t < BN) cmin[t] = ~0u;

  // ---- epilogue operands issued FIRST (oldest in vmcnt order; drained by
  // the iter-0 vmcnt wait, latency hidden under the K-loop) ----
  float sb[4];
#pragma unroll
  for (int y = 0; y < 4; ++y) sb[y] = sqB[colBase + wc * 64 + y * 16 + lc];
  float sa[4][4];
  if (!isProto) {
#pragma unroll
    for (int x = 0; x < 4; ++x)
#pragma unroll
      for (int r = 0; r < 4; ++r)
        sa[x][r] = sq[rowBase + wr * 64 + x * 16 + quad * 4 + r];
  }
  asm volatile("" ::: "memory");  // keep the loads above the staging issues

  // fragment-read unit offsets per 32-k chunk c: unit = (2c + quad/2) ^ (lc&7)
  int koff[4];
#pragma unroll
  for (int c = 0; c < 4; ++c)
    koff[c] = (((c * 2 + (quad >> 1)) ^ (lc & 7)) * 16) + (quad & 1) * 8;

  int rowA[4], rowB[4];
#pragma unroll
  for (int x = 0; x < 4; ++x) {
    rowA[x] = (wr * 64 + x * 16 + lc) * BK;  // 256 A-rows
    rowB[x] = (wc * 64 + x * 16 + lc) * BK;  // 128 B-rows
  }

  // staging: lane covers (row = rr*8 + lane/8, phys unit = lane&7);
  // logical source unit = (lane&7) ^ (row&7). Per K-tile: A = 32 rounds
  // (wave wv does wv*4..wv*4+3), B = 16 rounds (wv*2..wv*2+1).
  const int l8 = lane >> 3;
  const int ul = ((lane & 7) ^ l8) * 16;
  const unsigned char* gA = A + (size_t)(rowBase + l8) * DIM + ul;
  const unsigned char* gB = Bmat + (size_t)(colBase + l8) * DIM + ul;
  const int ldsL = lane * 16;

#define STAGE(buf, tt)                                                        \
  do {                                                                        \
    _Pragma("unroll") for (int j = 0; j < 4; ++j) {                           \
      const int rr = wv * 4 + j;                                              \
      async_ld16(gA + (size_t)rr * 8 * DIM + (size_t)(tt) * BK,               \
                 &As[buf][rr * 1024 + ldsL]);                                 \
    }                                                                         \
    _Pragma("unroll") for (int j = 0; j < 2; ++j) {                           \
      const int rr = wv * 2 + j;                                              \
      async_ld16(gB + (size_t)rr * 8 * DIM + (size_t)(tt) * BK,               \
                 &Bs[buf][rr * 1024 + ldsL]);                                 \
    }                                                                         \
  } while (0)

  f32x4 acc[4][4] = {};

  // prologue: stage K-tiles 0,1 into buffers 0,1 (6 loads each per wave)
  STAGE(0, 0);
  STAGE(1, 1);

#pragma unroll
  for (int it = 0; it < 4; ++it) {
    // drain this tile's 6 loads (and older); keep next tile's 6 in flight
    if (it < 3) VMWAIT_BAR(6);
    else        VMWAIT_BAR(0);
    if (it < 2) STAGE((it + 2) % NBUF, it + 2);  // tile it+2; buf reuse safe:
    // buf[(it+2)%3] held tile it-1, consumed before the barrier just crossed.
    const unsigned char* Ac = &As[it % NBUF][0];
    const unsigned char* Bc = &Bs[it % NBUF][0];
#pragma unroll
    for (int c = 0; c < 4; ++c) {
      long af[4], bfr[4];
#pragma unroll
      for (int x = 0; x < 4; ++x) {
        af[x]  = *(const long*)(Ac + rowA[x] + koff[c]);
        bfr[x] = *(const long*)(Bc + rowB[x] + koff[c]);
      }
      __builtin_amdgcn_s_setprio(1);
#pragma unroll
      for (int x = 0; x < 4; ++x)
#pragma unroll
        for (int y = 0; y < 4; ++y)
          acc[x][y] = __builtin_amdgcn_mfma_f32_16x16x32_fp8_fp8(
              af[x], bfr[y], acc[x][y], 0, 0, 0);
      __builtin_amdgcn_s_setprio(0);
    }
  }
#undef STAGE

  // ---- epilogue. C/D layout: col=lane&15, row=quad*4+reg ----
  const float INF = __int_as_float(0x7f800000);

  if (!isProto) {
    // row-side: butterfly min over the 16-lane quad, single-lane LDS atomic
#pragma unroll
    for (int x = 0; x < 4; ++x) {
#pragma unroll
      for (int r = 0; r < 4; ++r) {
        const int row = rowBase + wr * 64 + x * 16 + quad * 4 + r;
        float mv = INF, mx = -INF;
#pragma unroll
        for (int y = 0; y < 4; ++y) {
          const float v = fmaf(-2.f, acc[x][y][r], sb[y]);
          if (diagHalf) {
            const int col = colBase + wc * 64 + y * 16 + lc;
            const bool same = (row >> 3) == (col >> 3);
            mv = fminf(mv, same ? INF : v);
            mx = fmaxf(mx, same ? v : -INF);
          } else {
            mv = fminf(mv, v);
          }
        }
#pragma unroll
        for (int s = 1; s < 16; s <<= 1) {
          mv = fminf(mv, __shfl_xor(mv, s, 64));
          if (diagHalf) mx = fmaxf(mx, __shfl_xor(mx, s, 64));
        }
        if (lc == 0) {
          atomicMin(&rmin[row - rowBase], f2o(mv));
          if (diagHalf) atomicMax(&amax[row - rowBase], f2o(mx));
        }
      }
    }
    // col-side: only off-diagonal halves feed column mins (mirror pairs)
    if (!diagHalf) {
#pragma unroll
      for (int y = 0; y < 4; ++y) {
        float cv = INF;
#pragma unroll
        for (int x = 0; x < 4; ++x)
#pragma unroll
          for (int r = 0; r < 4; ++r)
            cv = fminf(cv, fmaf(-2.f, acc[x][y][r], sa[x][r]));
        cv = fminf(cv, __shfl_xor(cv, 16, 64));
        cv = fminf(cv, __shfl_xor(cv, 32, 64));
        if (quad == 0) atomicMin(&cmin[wc * 64 + y * 16 + lc], f2o(cv));
      }
    }
  } else {
    // proto path: argmin index -> u64 keys + 16-lane butterfly
#pragma unroll
    for (int x = 0; x < 4; ++x) {
      unsigned long long kmin[4] = {~0ull, ~0ull, ~0ull, ~0ull};
#pragma unroll
      for (int y = 0; y < 4; ++y) {
        const int col = colBase + wc * 64 + y * 16 + lc;
#pragma unroll
        for (int r = 0; r < 4; ++r) {
          const float v = fmaf(-2.f, acc[x][y][r], sb[y]);
          const unsigned long long kn =
              ((unsigned long long)f2o(v) << 32) | (unsigned)col;
          if (kn < kmin[r]) kmin[r] = kn;
        }
      }
#pragma unroll
      for (int r = 0; r < 4; ++r) {
#pragma unroll
        for (int s = 1; s < 16; s <<= 1) {
          const unsigned long long o = __shfl_xor(kmin[r], s, 64);
          if (o < kmin[r]) kmin[r] = o;
        }
      }
      if (lc == 0) {
#pragma unroll
        for (int r = 0; r < 4; ++r)
          rowkey[wr * 64 + x * 16 + quad * 4 + r][wc] = kmin[r];
      }
    }
  }

  __syncthreads();
  if (isProto) {
    if (t < BM) {
      unsigned long long a = rowkey[t][0];
      const unsigned long long c = rowkey[t][1];
      if (c < a) a = c;
      atomicMin(pr_key + rowBase + t, a);
    }
  } else {
    if (t < BM) {
      atomicMin(an_u32 + rowBase + t, rmin[t]);
    } else if (t < BM + BN) {
      atomicMin(an_u32 + colBase + (t - BM), cmin[t - BM]);
    } else if (hasDiag && t < BM + BN + 128) {
      const int i = dh * 128 + (t - BM - BN);
      atomicMax(ap_u32 + rowBase + i, amax[i]);
    }
  }
}

// ---- final scalar reductions ----
__global__ void finalize_kernel(const float* __restrict__ sq,
                                const unsigned* __restrict__ an_u32,
                                const unsigned* __restrict__ ap_u32,
                                const unsigned long long* __restrict__ pr_key,
                                float* __restrict__ out) {
  const int tid = threadIdx.x;  // 1024 threads
  float loss = 0.f, sp = 0.f, sn = 0.f, acc = 0.f;
#pragma unroll
  for (int i = tid; i < NTOT; i += 1024) {
    const float s = sq[i];
    const float ap = sqrtf(fmaxf(s + o2f(ap_u32[i]), 1e-12f));
    const float an = sqrtf(fmaxf(s + o2f(an_u32[i]), 1e-12f));
    loss += fmaxf(ap - an + MARGINV, 0.f);
    sp += ap;
    sn += an;
    acc += ((unsigned)(pr_key[i] & 0xffffffffu) == (unsigned)(i >> 3)) ? 1.f : 0.f;
  }
  loss = wave_sum64(loss);
  sp = wave_sum64(sp);
  sn = wave_sum64(sn);
  acc = wave_sum64(acc);
  __shared__ float red[16][4];
  const int w = tid >> 6, l = tid & 63;
  if (l == 0) { red[w][0] = loss; red[w][1] = acc; red[w][2] = sp; red[w][3] = sn; }
  __syncthreads();
  if (tid == 0) {
    float L = 0, Ac = 0, Pm = 0, Nn = 0;
    for (int i = 0; i < 16; ++i) {
      L += red[i][0]; Ac += red[i][1]; Pm += red[i][2]; Nn += red[i][3];
    }
    out[0] = L / NTOT;   // W = 1.0
    out[1] = Ac / NTOT;
    out[2] = Pm / NTOT;
    out[3] = Nn / NTOT;
  }
}

extern "C" void kernel_launch(void* const* d_in, const int* in_sizes, int n_in,
                              void* d_out, int out_size, void* d_ws, size_t ws_size,
                              hipStream_t stream) {
  const float* inputs = (const float*)d_in[0];
  float* out = (float*)d_out;
  char* w = (char*)d_ws;
  float* sq  = (float*)(w);                                       // 32 KB
  float* psq = (float*)(w + 32768);                               // 4 KB
  unsigned* an_u32 = (unsigned*)(w + 36864);                      // 32 KB
  unsigned* ap_u32 = (unsigned*)(w + 69632);                      // 32 KB
  unsigned long long* pr_key = (unsigned long long*)(w + 102400); // 64 KB
  unsigned char* A8 = (unsigned char*)(w + 167936);               // 4 MB
  unsigned char* P8 = (unsigned char*)(w + 167936 + (size_t)NTOT * DIM);

  prep<<<NTOT / 4 + NWAYS / 4, 256, 0, stream>>>(inputs, sq, psq, A8, P8,
                                                 an_u32, ap_u32, pr_key);
  gemm_fused<<<NBLK2, 512, 0, stream>>>(A8, P8, sq, psq,
                                        an_u32, ap_u32, pr_key);
  finalize_kernel<<<1, 1024, 0, stream>>>(sq, an_u32, ap_u32, pr_key, out);
}

// Round 5
// 143.809 us; speedup vs baseline: 1.0389x; 1.0041x over previous
//
#include <hip/hip_runtime.h>
#include <hip/hip_bf16.h>
#include <stdint.h>

#define NTOT  8192
#define DIM   512
#define NI    8
#define NWAYS 1024
#define BM    256
#define BN    128
#define BK    64
#define NJOBS 1312   /* sum_I (64-2I + 8) = 1056 sym + 256 proto, I=0..31 */
#define MARGINV 0.3f

typedef float f32x4 __attribute__((ext_vector_type(4)));

// counted-vmcnt barrier: one asm so nothing schedules between wait and barrier
#define VMWAIT_BAR(N) \
  asm volatile("s_waitcnt vmcnt(" #N ")\n\ts_barrier" ::: "memory")
#define SBAR() asm volatile("s_barrier" ::: "memory")

// order-preserving float<->uint map (monotonic for all finite floats +/- inf)
__device__ __forceinline__ unsigned f2o(float f) {
  unsigned u = __float_as_uint(f);
  return (u & 0x80000000u) ? ~u : (u | 0x80000000u);
}
__device__ __forceinline__ float o2f(unsigned u) {
  u = (u & 0x80000000u) ? (u & 0x7fffffffu) : ~u;
  return __uint_as_float(u);
}

__device__ __forceinline__ float wave_sum64(float v) {
#pragma unroll
  for (int s = 32; s; s >>= 1) v += __shfl_xor(v, s, 64);
  return v;
}

__device__ __forceinline__ void async_ld16(const void* g, void* l) {
  __builtin_amdgcn_global_load_lds(
      (__attribute__((address_space(1))) void*)(uintptr_t)g,
      (__attribute__((address_space(3))) void*)l, 16, 0, 0);
}

// ---- prep: sq-norms + fp8(e4m3) cast + accumulator init; protos in tail ----
__global__ __launch_bounds__(256) void prep(
    const float* __restrict__ A, float* __restrict__ sq,
    float* __restrict__ psq, unsigned char* __restrict__ A8,
    unsigned char* __restrict__ P8,
    unsigned* __restrict__ an_u32, unsigned* __restrict__ ap_u32,
    unsigned long long* __restrict__ pr_key) {
  const int w = threadIdx.x >> 6;
  const int l = threadIdx.x & 63;
  const int b = blockIdx.x;
  if (b < NTOT / 4) {
    const int row = b * 4 + w;
    const float4* rp = (const float4*)(A + (size_t)row * DIM);
    unsigned* op = (unsigned*)(A8 + (size_t)row * DIM);
    float s = 0.f;
#pragma unroll
    for (int m = 0; m < 2; ++m) {
      const float4 v = rp[l + 64 * m];
      s = fmaf(v.x, v.x, fmaf(v.y, v.y, fmaf(v.z, v.z, fmaf(v.w, v.w, s))));
      int wd = 0;
      wd = __builtin_amdgcn_cvt_pk_fp8_f32(v.x, v.y, wd, false);
      wd = __builtin_amdgcn_cvt_pk_fp8_f32(v.z, v.w, wd, true);
      op[l + 64 * m] = (unsigned)wd;
    }
    s = wave_sum64(s);
    if (l == 0) {
      sq[row] = s;
      an_u32[row] = ~0u;
      ap_u32[row] = 0u;
      pr_key[row] = ~0ull;
    }
  } else {
    const int c = (b - NTOT / 4) * 4 + w;  // proto id
    unsigned* op = (unsigned*)(P8 + (size_t)c * DIM);
    float s = 0.f;
#pragma unroll
    for (int m = 0; m < 2; ++m) {
      float4 p = {0.f, 0.f, 0.f, 0.f};
#pragma unroll
      for (int r = 0; r < NI; ++r) {
        const float4 v =
            ((const float4*)(A + (size_t)(c * NI + r) * DIM))[l + 64 * m];
        p.x += v.x; p.y += v.y; p.z += v.z; p.w += v.w;
      }
      p.x *= (1.f / NI); p.y *= (1.f / NI); p.z *= (1.f / NI); p.w *= (1.f / NI);
      s = fmaf(p.x, p.x, fmaf(p.y, p.y, fmaf(p.z, p.z, fmaf(p.w, p.w, s))));
      int wd = 0;
      wd = __builtin_amdgcn_cvt_pk_fp8_f32(p.x, p.y, wd, false);
      wd = __builtin_amdgcn_cvt_pk_fp8_f32(p.z, p.w, wd, true);
      op[l + 64 * m] = (unsigned)wd;
    }
    s = wave_sum64(s);
    if (l == 0) psq[c] = s;
  }
}

// ---- persistent-block fused GEMM ----
// 256 blocks (1/CU, single round). Block holds a 256x512 fp8 A-panel
// RESIDENT in LDS (128 KB) and iterates ~5 contiguous tile-jobs, streaming
// the 128x512 B-panel through a 3-slot ring of 8 KB BK=64 chunks with
// counted vmcnt(1) (chunk issued 2 steps ahead). A-staging is amortized
// across jobs; epilogue goes straight to global atomics (no LDS arrays).
// Jobs: panel I (I=0..31) has (64-2I) sym tiles (J=2I..63) then 8 proto
// tiles; prefix S(I)=I*(73-I); block b covers jobs [b*41/8, (b+1)*41/8).
// XCD map b=(braw&7)*32+(braw>>3): each XCD gets a contiguous job range
// (~2.3 A-panels) for L2 reuse.
// LDS swizzles (verified in prior rounds, absmax 0):
//  A rows 512 B = 32 x 16-B units, phys unit = logical ^ (row&7);
//  B rows  64 B =  4 x 16-B units, phys unit = logical ^ ((row^(row>>2))&3).
// Fragment ds_read_b64 is 2-lanes/bank (free) for both.
__global__ __launch_bounds__(512) void gemm_fused(
    const unsigned char* __restrict__ A, const unsigned char* __restrict__ P,
    const float* __restrict__ sq, const float* __restrict__ psq,
    unsigned* __restrict__ an_u32, unsigned* __restrict__ ap_u32,
    unsigned long long* __restrict__ pr_key) {
  __shared__ __align__(16) unsigned char As[BM * DIM];    // 131072
  __shared__ __align__(16) unsigned char Bs[3][BN * BK];  // 24576

  const int braw = blockIdx.x;
  const int b = (braw & 7) * 32 + (braw >> 3);
  int job = (b * 41) >> 3;
  const int jend = ((b + 1) * 41) >> 3;

  const int t = threadIdx.x;  // 512 = 8 waves
  const int lane = t & 63;
  const int wv = t >> 6;
  const int wr = wv >> 1;     // 0..3: 64-row slice of 256
  const int wc = wv & 1;      // 0..1: 64-col slice of 128
  const int quad = lane >> 4;
  const int lc = lane & 15;

  // fragment-read constants
  int koffA[16];
#pragma unroll
  for (int c = 0; c < 16; ++c)
    koffA[c] = (((2 * c + (quad >> 1)) ^ (lc & 7)) << 4) + (quad & 1) * 8;
  const int kf = (lc ^ (lc >> 2)) & 3;
  int koffB[2];
#pragma unroll
  for (int cc = 0; cc < 2; ++cc)
    koffB[cc] = (((cc * 2 + (quad >> 1)) ^ kf) << 4) + (quad & 1) * 8;
  int rowA[4], rowB[4];
#pragma unroll
  for (int x = 0; x < 4; ++x) {
    rowA[x] = (wr * 64 + x * 16 + lc) * DIM;
    rowB[x] = (wc * 64 + x * 16 + lc) * BK;
  }

  // B staging constants: per instr, lane covers (row = wv*16 + lane/4,
  // phys unit = lane&3); source unit pre-swizzled.
  const int bRow = wv * 16 + (lane >> 2);
  const int bSu = ((lane & 3) ^ ((bRow ^ (bRow >> 2)) & 3)) << 4;
  unsigned char* const bDst = &Bs[0][0] + wv * 1024 + lane * 16;
  const int l32 = lane >> 5;  // A staging: 2 rows per instr

  const float INF = __int_as_float(0x7f800000);

  int curI = -1;
  float sa[4][4];

  for (; job < jend; ++job) {
    // ---- decode job -> panel I, tile ----
    int I = 0;
    while ((I + 1) * (72 - I) <= job) ++I;  // S(I+1) = (I+1)*(72-I)
    const int jl = job - I * (73 - I);
    const bool sym = jl < 64 - 2 * I;
    const int rowBase = I * BM;
    const int colBase = (sym ? (2 * I + jl) : (jl - (64 - 2 * I))) * BN;
    const unsigned char* Bsrc = sym ? A : P;
    const float* sqB = sym ? sq : psq;
    const bool diagHalf = sym && (jl == (wr >> 1));  // wave's 128-half on diag

    if (I != curI) {  // (re)stage A-panel; prior job's LDS reads done (SBAR)
      curI = I;
      const unsigned char* gAp = A + (size_t)rowBase * DIM;
#pragma unroll
      for (int j = 0; j < 16; ++j) {
        const int row = wv * 32 + 2 * j + l32;
        async_ld16(gAp + (size_t)row * DIM + (((lane & 31) ^ (row & 7)) << 4),
                   &As[(wv * 32 + 2 * j) * DIM + lane * 16]);
      }
#pragma unroll
      for (int x = 0; x < 4; ++x)
#pragma unroll
        for (int r = 0; r < 4; ++r)
          sa[x][r] = sq[rowBase + wr * 64 + x * 16 + quad * 4 + r];
    }

    float sb[4];
#pragma unroll
    for (int y = 0; y < 4; ++y) sb[y] = sqB[colBase + wc * 64 + y * 16 + lc];

    const unsigned char* gB = Bsrc + (size_t)(colBase + bRow) * DIM + bSu;
    async_ld16(gB + 0 * BK, bDst + 0 * 8192);  // chunk 0 -> slot 0
    async_ld16(gB + 1 * BK, bDst + 1 * 8192);  // chunk 1 -> slot 1

    f32x4 acc[4][4] = {};
#pragma unroll
    for (int kt = 0; kt < 8; ++kt) {
      // drain chunk kt (and all older VMEM: A-panel, sb, prior atomics);
      // chunk kt+1 stays in flight
      if (kt < 7) VMWAIT_BAR(1);
      else        VMWAIT_BAR(0);
      if (kt < 6)  // issue chunk kt+2; its slot's last reader was step kt-1
        async_ld16(gB + (size_t)(kt + 2) * BK, bDst + ((kt + 2) % 3) * 8192);
      const unsigned char* Bc = &Bs[kt % 3][0];
#pragma unroll
      for (int cc = 0; cc < 2; ++cc) {
        long af[4], bf[4];
#pragma unroll
        for (int x = 0; x < 4; ++x) {
          af[x] = *(const long*)(As + rowA[x] + koffA[kt * 2 + cc]);
          bf[x] = *(const long*)(Bc + rowB[x] + koffB[cc]);
        }
        __builtin_amdgcn_s_setprio(1);
#pragma unroll
        for (int x = 0; x < 4; ++x)
#pragma unroll
          for (int y = 0; y < 4; ++y)
            acc[x][y] = __builtin_amdgcn_mfma_f32_16x16x32_fp8_fp8(
                af[x], bf[y], acc[x][y], 0, 0, 0);
        __builtin_amdgcn_s_setprio(0);
      }
    }
    SBAR();  // all waves' LDS reads complete -> ring/panel reusable

    // ---- epilogue. C/D layout: col=lane&15, row=quad*4+reg ----
    if (sym) {
      // row-side: butterfly min over quad's 16 cols, then 1 lane -> global
#pragma unroll
      for (int x = 0; x < 4; ++x) {
#pragma unroll
        for (int r = 0; r < 4; ++r) {
          const int row = rowBase + wr * 64 + x * 16 + quad * 4 + r;
          float mv = INF, mx = -INF;
#pragma unroll
          for (int y = 0; y < 4; ++y) {
            const float v = fmaf(-2.f, acc[x][y][r], sb[y]);
            if (diagHalf) {
              const int col = colBase + wc * 64 + y * 16 + lc;
              const bool same = (row >> 3) == (col >> 3);
              mv = fminf(mv, same ? INF : v);
              mx = fmaxf(mx, same ? v : -INF);
            } else {
              mv = fminf(mv, v);
            }
          }
#pragma unroll
          for (int s = 1; s < 16; s <<= 1) {
            mv = fminf(mv, __shfl_xor(mv, s, 64));
            if (diagHalf) mx = fmaxf(mx, __shfl_xor(mx, s, 64));
          }
          if (lc == 0) {
            atomicMin(&an_u32[row], f2o(mv));
            if (diagHalf) atomicMax(&ap_u32[row], f2o(mx));
          }
        }
      }
      // col-side (off-diag halves): reduce across quads, quad 0 -> global
      if (!diagHalf) {
#pragma unroll
        for (int y = 0; y < 4; ++y) {
          float cv = INF;
#pragma unroll
          for (int x = 0; x < 4; ++x)
#pragma unroll
            for (int r = 0; r < 4; ++r)
              cv = fminf(cv, fmaf(-2.f, acc[x][y][r], sa[x][r]));
          cv = fminf(cv, __shfl_xor(cv, 16, 64));
          cv = fminf(cv, __shfl_xor(cv, 32, 64));
          if (quad == 0)
            atomicMin(&an_u32[colBase + wc * 64 + y * 16 + lc], f2o(cv));
        }
      }
    } else {
      // proto path: argmin via u64 keys + 16-lane butterfly -> global u64 min
#pragma unroll
      for (int x = 0; x < 4; ++x) {
        unsigned long long kmin[4] = {~0ull, ~0ull, ~0ull, ~0ull};
#pragma unroll
        for (int y = 0; y < 4; ++y) {
          const int col = colBase + wc * 64 + y * 16 + lc;
#pragma unroll
          for (int r = 0; r < 4; ++r) {
            const float v = fmaf(-2.f, acc[x][y][r], sb[y]);
            const unsigned long long kn =
                ((unsigned long long)f2o(v) << 32) | (unsigned)col;
            if (kn < kmin[r]) kmin[r] = kn;
          }
        }
#pragma unroll
        for (int r = 0; r < 4; ++r) {
#pragma unroll
          for (int s = 1; s < 16; s <<= 1) {
            const unsigned long long o = __shfl_xor(kmin[r], s, 64);
            if (o < kmin[r]) kmin[r] = o;
          }
          if (lc == 0) {
            const int row = rowBase + wr * 64 + x * 16 + quad * 4 + r;
            atomicMin(&pr_key[row], kmin[r]);
          }
        }
      }
    }
  }
}

// ---- final scalar reductions ----
__global__ void finalize_kernel(const float* __restrict__ sq,
                                const unsigned* __restrict__ an_u32,
                                const unsigned* __restrict__ ap_u32,
                                const unsigned long long* __restrict__ pr_key,
                                float* __restrict__ out) {
  const int tid = threadIdx.x;  // 1024 threads
  float loss = 0.f, sp = 0.f, sn = 0.f, acc = 0.f;
#pragma unroll
  for (int i = tid; i < NTOT; i += 1024) {
    const float s = sq[i];
    const float ap = sqrtf(fmaxf(s + o2f(ap_u32[i]), 1e-12f));
    const float an = sqrtf(fmaxf(s + o2f(an_u32[i]), 1e-12f));
    loss += fmaxf(ap - an + MARGINV, 0.f);
    sp += ap;
    sn += an;
    acc += ((unsigned)(pr_key[i] & 0xffffffffu) == (unsigned)(i >> 3)) ? 1.f : 0.f;
  }
  loss = wave_sum64(loss);
  sp = wave_sum64(sp);
  sn = wave_sum64(sn);
  acc = wave_sum64(acc);
  __shared__ float red[16][4];
  const int w = tid >> 6, l = tid & 63;
  if (l == 0) { red[w][0] = loss; red[w][1] = acc; red[w][2] = sp; red[w][3] = sn; }
  __syncthreads();
  if (tid == 0) {
    float L = 0, Ac = 0, Pm = 0, Nn = 0;
    for (int i = 0; i < 16; ++i) {
      L += red[i][0]; Ac += red[i][1]; Pm += red[i][2]; Nn += red[i][3];
    }
    out[0] = L / NTOT;   // W = 1.0
    out[1] = Ac / NTOT;
    out[2] = Pm / NTOT;
    out[3] = Nn / NTOT;
  }
}

extern "C" void kernel_launch(void* const* d_in, const int* in_sizes, int n_in,
                              void* d_out, int out_size, void* d_ws, size_t ws_size,
                              hipStream_t stream) {
  const float* inputs = (const float*)d_in[0];
  float* out = (float*)d_out;
  char* w = (char*)d_ws;
  float* sq  = (float*)(w);                                       // 32 KB
  float* psq = (float*)(w + 32768);                               // 4 KB
  unsigned* an_u32 = (unsigned*)(w + 36864);                      // 32 KB
  unsigned* ap_u32 = (unsigned*)(w + 69632);                      // 32 KB
  unsigned long long* pr_key = (unsigned long long*)(w + 102400); // 64 KB
  unsigned char* A8 = (unsigned char*)(w + 167936);               // 4 MB
  unsigned char* P8 = (unsigned char*)(w + 167936 + (size_t)NTOT * DIM);

  prep<<<NTOT / 4 + NWAYS / 4, 256, 0, stream>>>(inputs, sq, psq, A8, P8,
                                                 an_u32, ap_u32, pr_key);
  gemm_fused<<<256, 512, 0, stream>>>(A8, P8, sq, psq,
                                      an_u32, ap_u32, pr_key);
  finalize_kernel<<<1, 1024, 0, stream>>>(sq, an_u32, ap_u32, pr_key, out);
}